// Round 1
// baseline (9700.668 us; speedup 1.0000x reference)
//
#include <hip/hip_runtime.h>
#include <hip/hip_bf16.h>
#include <math.h>

// Problem constants (fixed by reference: x,y are (4096, 512) fp32)
#define N 4096
#define D 512
#define SINK_PASSES 100           // 50 iterations x (f-update, g-update)

// log-domain constants (base-2 internally; v_exp_f32/v_log_f32 are base-2)
#define K_LOG2 14.426950408889634f          // (1/eps) * log2(e), eps = 0.1
#define TWO_K  28.853900817779268f          // 2 * K_LOG2
#define NEG_EPS_LN2 (-0.06931471805599453f) // -eps * ln(2)
#define EPS_NEG_LOGMU 0.8317766166719343f   // -eps * log_mu = eps * log(4096)

// Sparse-candidate machinery: entries with u < rowmax - MARGIN (log2 units)
// contribute < 2^-MARGIN each; MARGIN=600 covers potential drift between the
// two build events (p=9/10 and p=49/50) with >10x headroom (see R5/R6 absmax).
#define CAP 512
#define MARGIN 600.0f

typedef __bf16   bf16x8 __attribute__((ext_vector_type(8)));
typedef _Float16 halfx8 __attribute__((ext_vector_type(8)));
typedef float    floatx4 __attribute__((ext_vector_type(4)));
typedef unsigned short ushortx8v __attribute__((ext_vector_type(8)));

// ---------- convert fp32 -> bf16 (GEMM inputs) ----------
__global__ void cvt_bf16_kernel(const float* __restrict__ in, __bf16* __restrict__ out, int count) {
    int idx = blockIdx.x * blockDim.x + threadIdx.x;
    if (idx < count) out[idx] = (__bf16)in[idx];
}

// ---------- row squared norms (fp32 inputs, exact) ----------
__global__ void sqnorm_kernel(const float* __restrict__ in, float* __restrict__ out) {
    int row = blockIdx.x;
    const float* p = in + (size_t)row * D;
    float s = 0.f;
    for (int k = threadIdx.x; k < D; k += 64) { float v = p[k]; s += v * v; }
    for (int off = 32; off > 0; off >>= 1) s += __shfl_down(s, off);
    if (threadIdx.x == 0) out[row] = s;
}

// ---------- 128x128-tile GEMM: out = A @ B^T (fp16), writes tile + transposed tile ----------
// (round-4 proven; sym=1 computes upper-triangle blocks + mirror writes)
__global__ __launch_bounds__(256) void gemm128_kernel(
    const __bf16* __restrict__ A, const __bf16* __restrict__ Bm,
    _Float16* __restrict__ out1, _Float16* __restrict__ out2, int sym) {
    if (sym && blockIdx.x > blockIdx.y) return;
    __shared__ char smem[34816];
    __bf16* ldsA = (__bf16*)smem;           // [128][64] swizzled
    __bf16* ldsB = ldsA + 128 * 64;

    int t = threadIdx.x;
    int w = t >> 6, lane = t & 63;
    int m = lane & 15, q = lane >> 4;
    int wr = w & 1, wc = w >> 1;
    int m0 = blockIdx.x * 128, n0 = blockIdx.y * 128;

    int srow = t >> 1, shalf = t & 1;
    const bf16x8* gA = (const bf16x8*)(A  + (size_t)(m0 + srow) * D + shalf * 32);
    const bf16x8* gB = (const bf16x8*)(Bm + (size_t)(n0 + srow) * D + shalf * 32);

    floatx4 acc[4][4];
#pragma unroll
    for (int i = 0; i < 4; i++)
#pragma unroll
        for (int j = 0; j < 4; j++) acc[i][j] = (floatx4){0.f, 0.f, 0.f, 0.f};

    for (int slab = 0; slab < 8; slab++) {
        bf16x8 va[4], vb[4];
#pragma unroll
        for (int i = 0; i < 4; i++) {
            va[i] = gA[slab * 8 + i];
            vb[i] = gB[slab * 8 + i];
        }
        __syncthreads();
#pragma unroll
        for (int i = 0; i < 4; i++) {
            int cp = (shalf * 4 + i) ^ (srow & 7);
            *(bf16x8*)(ldsA + srow * 64 + cp * 8) = va[i];
            *(bf16x8*)(ldsB + srow * 64 + cp * 8) = vb[i];
        }
        __syncthreads();
#pragma unroll
        for (int kk = 0; kk < 2; kk++) {
            bf16x8 af[4], bfr[4];
#pragma unroll
            for (int mt = 0; mt < 4; mt++) {
                int cp = (kk * 4 + q) ^ (m & 7);
                af[mt]  = *(const bf16x8*)(ldsA + (wr * 64 + mt * 16 + m) * 64 + cp * 8);
                bfr[mt] = *(const bf16x8*)(ldsB + (wc * 64 + mt * 16 + m) * 64 + cp * 8);
            }
#pragma unroll
            for (int mt = 0; mt < 4; mt++)
#pragma unroll
                for (int nt = 0; nt < 4; nt++)
                    acc[mt][nt] = __builtin_amdgcn_mfma_f32_16x16x32_bf16(
                        af[mt], bfr[nt], acc[mt][nt], 0, 0, 0);
        }
    }

    __syncthreads();
    _Float16* et = (_Float16*)smem + w * (64 * 66);
#pragma unroll
    for (int mt = 0; mt < 4; mt++)
#pragma unroll
        for (int nt = 0; nt < 4; nt++)
#pragma unroll
            for (int r = 0; r < 4; r++)
                et[(mt * 16 + q * 4 + r) * 66 + nt * 16 + m] = (_Float16)acc[mt][nt][r];

    int l3 = lane >> 3, c8 = lane & 7;
#pragma unroll
    for (int rr = 0; rr < 8; rr++) {
        int rl = rr * 8 + l3;
        halfx8 v = *(const halfx8*)(et + rl * 66 + c8 * 8);
        *(halfx8*)(out1 + (size_t)(m0 + wr * 64 + rl) * N + n0 + wc * 64 + c8 * 8) = v;
    }
#pragma unroll
    for (int rr = 0; rr < 8; rr++) {
        int rT = rr * 8 + l3;
        halfx8 v;
#pragma unroll
        for (int k = 0; k < 8; k++) v[k] = et[(c8 * 8 + k) * 66 + rT];
        *(halfx8*)(out2 + (size_t)(n0 + wc * 64 + rT) * N + m0 + wr * 64 + c8 * 8) = v;
    }
}

// ---------- full Sinkhorn pass (3 pairs, 1 row/wave, 3072 blocks) ----------
// gyk staged TRANSPOSED in LDS: gykT[k][j>>3] so the read gykT[k*512+chunk]
// is lane-consecutive -> conflict-free (the old layout was 16-way conflicted).
// BUILD=1: collect candidates u >= prevmax - MARGIN via ballot compaction,
// with a chunk-level ballot skip (hits are rare). Every variant stores this
// pass's row max into prevmax[].
template<int BUILD>
__global__ __launch_bounds__(256) void lse_full3_kernel(
    const _Float16* __restrict__ Sxy, const _Float16* __restrict__ STxy,
    const _Float16* __restrict__ Sxx, const _Float16* __restrict__ Syy,
    const float* __restrict__ x2, const float* __restrict__ y2,
    float* __restrict__ Pxy0, float* __restrict__ Pxy1,
    float* __restrict__ Pxx0, float* __restrict__ Pxx1,
    float* __restrict__ Pyy0, float* __restrict__ Pyy1,
    int odd,
    unsigned int* __restrict__ cand, int* __restrict__ cnt,
    float* __restrict__ prevmax) {
    __shared__ float gykT[8 * 512];
    int pair = blockIdx.x >> 10;
    int blk = blockIdx.x & 1023;
    const _Float16* M;
    const float *own, *other, *pin;
    float* pout;
    if (pair == 0) {
        if (odd) { M = Sxy;  own = x2; other = y2; pin = Pxy0; pout = Pxy1; }
        else     { M = STxy; own = y2; other = x2; pin = Pxy1; pout = Pxy0; }
    } else if (pair == 1) {
        M = Sxx; own = x2; other = x2;
        if (odd) { pin = Pxx0; pout = Pxx1; } else { pin = Pxx1; pout = Pxx0; }
    } else {
        M = Syy; own = y2; other = y2;
        if (odd) { pin = Pyy0; pout = Pyy1; } else { pin = Pyy1; pout = Pyy0; }
    }

    int wave = threadIdx.x >> 6, lane = threadIdx.x & 63;

    {   // stage gykT[(j&7)*512 + (j>>3)] = (pin[j] - other[j]) * K
        const floatx4* pi4 = (const floatx4*)pin;
        const floatx4* so4 = (const floatx4*)other;
        for (int tt = threadIdx.x; tt < N / 4; tt += 256) {
            floatx4 p = pi4[tt], o = so4[tt];
            int j = tt * 4;
#pragma unroll
            for (int k2 = 0; k2 < 4; k2++) {
                int jj = j + k2;
                gykT[(jj & 7) * 512 + (jj >> 3)] = (p[k2] - o[k2]) * K_LOG2;
            }
        }
    }
    __syncthreads();

    int row = blk * 4 + wave;
    int set = pair * 2 + (odd ? 0 : 1);
    int idx = set * N + row;
    float thr = 0.f;
    size_t cbase = 0;
    int ncand = 0;
    unsigned long long lt_mask = (1ull << lane) - 1ull;
    if (BUILD) { thr = prevmax[idx] - MARGIN; cbase = (size_t)idx * CAP; }

    const halfx8* srow = (const halfx8*)(M + (size_t)row * N);
    float m = -INFINITY, s = 0.f;
#pragma unroll
    for (int c = 0; c < 8; c++) {
        int chunk = c * 64 + lane;
        halfx8 sv = srow[chunk];
        int j0 = chunk * 8;
        float u[8];
#pragma unroll
        for (int k = 0; k < 8; k++)
            u[k] = fmaf((float)sv[k], TWO_K, gykT[k * 512 + chunk]);
        float mloc = fmaxf(fmaxf(fmaxf(u[0], u[1]), fmaxf(u[2], u[3])),
                           fmaxf(fmaxf(u[4], u[5]), fmaxf(u[6], u[7])));
        if (BUILD) {
            // chunk-level skip: only run the serialized per-k ballots if some
            // lane in the wave has a hit in this chunk (hits are rare).
            if (__ballot(mloc >= thr)) {
                ushortx8v sb = __builtin_bit_cast(ushortx8v, sv);
#pragma unroll
                for (int k = 0; k < 8; k++) {
                    bool hit = (u[k] >= thr);
                    unsigned long long mask = __ballot(hit);
                    if (hit) {
                        int slot = ncand + __popcll(mask & lt_mask);
                        if (slot < CAP)
                            cand[cbase + slot] = ((unsigned int)(j0 + k) << 16) | (unsigned int)sb[k];
                    }
                    ncand += (int)__popcll(mask);
                }
            }
        }
        float M2 = fmaxf(m, mloc);
        float acc = 0.f;
#pragma unroll
        for (int k = 0; k < 8; k++) acc += exp2f(u[k] - M2);
        s = s * exp2f(m - M2) + acc;
        m = M2;
    }
    for (int off = 32; off > 0; off >>= 1) {
        float m2 = __shfl_down(m, off), s2 = __shfl_down(s, off);
        float Mx = fmaxf(m, m2);
        s = s * exp2f(m - Mx) + s2 * exp2f(m2 - Mx);
        m = Mx;
    }
    if (lane == 0) {
        float xk = own[row] * K_LOG2;
        pout[row] = NEG_EPS_LN2 * (m + __log2f(s) - xk) + EPS_NEG_LOGMU;
        prevmax[idx] = m;
        if (BUILD) cnt[idx] = ncand;
    }
}

// ---------- shared sparse-pass row body: one wave processes rows pwave*4..+3 ----------
// Per candidate: gather pin[j], other[j] directly (16KB arrays, cache-hot).
// Batched u[8] in registers, wave-wide shfl_xor max then sum.
// Dense fallback (direct global reads) when cnt==0 or cnt>CAP.
__device__ __forceinline__ void sparse_rows4(
    const _Float16* __restrict__ M, const float* __restrict__ own,
    const float* __restrict__ other, const float* __restrict__ pin,
    float* __restrict__ pout, int set, int pwave, int lane,
    const unsigned int* __restrict__ cand, const int* __restrict__ cnt,
    float* __restrict__ prevmax) {
    for (int i = 0; i < 4; i++) {
        int row = pwave * 4 + i;
        int idx = set * N + row;
        int c = cnt[idx];
        float m, s;
        if (c >= 1 && c <= CAP) {
            size_t cbase = (size_t)idx * CAP;
            int nb = (c + 63) >> 6;
            float uu[8];
            float lm = -INFINITY;
#pragma unroll 8
            for (int b = 0; b < 8; b++) {
                uu[b] = -INFINITY;
                if (b < nb) {
                    int t = b * 64 + lane;
                    if (t < c) {
                        unsigned int pk = cand[cbase + t];
                        int j = pk >> 16;
                        _Float16 h = __builtin_bit_cast(_Float16, (unsigned short)(pk & 0xffffu));
                        uu[b] = fmaf((float)h, TWO_K, (pin[j] - other[j]) * K_LOG2);
                    }
                    lm = fmaxf(lm, uu[b]);
                }
            }
            // wave-wide max (butterfly: all lanes get result)
            for (int off = 32; off > 0; off >>= 1)
                lm = fmaxf(lm, __shfl_xor(lm, off));
            float ls = 0.f;
#pragma unroll 8
            for (int b = 0; b < 8; b++)
                if (b < nb) ls += exp2f(uu[b] - lm);   // -inf -> 0
            for (int off = 32; off > 0; off >>= 1)
                ls += __shfl_xor(ls, off);
            m = lm; s = ls;
        } else {
            // dense fallback: direct global reads (rare)
            m = -INFINITY; s = 0.f;
            const halfx8* rowp = (const halfx8*)(M + (size_t)row * N);
            for (int ch = lane; ch < N / 8; ch += 64) {
                halfx8 sv = rowp[ch];
                int j0 = ch * 8;
                floatx4 p0 = *(const floatx4*)(pin + j0);
                floatx4 p1 = *(const floatx4*)(pin + j0 + 4);
                floatx4 o0 = *(const floatx4*)(other + j0);
                floatx4 o1 = *(const floatx4*)(other + j0 + 4);
                float u[8];
#pragma unroll
                for (int k = 0; k < 4; k++) {
                    u[k]     = fmaf((float)sv[k],     TWO_K, (p0[k] - o0[k]) * K_LOG2);
                    u[k + 4] = fmaf((float)sv[k + 4], TWO_K, (p1[k] - o1[k]) * K_LOG2);
                }
                float mloc = fmaxf(fmaxf(fmaxf(u[0], u[1]), fmaxf(u[2], u[3])),
                                   fmaxf(fmaxf(u[4], u[5]), fmaxf(u[6], u[7])));
                float M2 = fmaxf(m, mloc);
                float acc = 0.f;
#pragma unroll
                for (int k = 0; k < 8; k++) acc += exp2f(u[k] - M2);
                s = s * exp2f(m - M2) + acc;
                m = M2;
            }
            for (int off = 32; off > 0; off >>= 1) {
                float m2 = __shfl_xor(m, off), s2 = __shfl_xor(s, off);
                float Mx = fmaxf(m, m2);
                float a1 = (m  == -INFINITY) ? 0.f : s  * exp2f(m  - Mx);
                float a2 = (m2 == -INFINITY) ? 0.f : s2 * exp2f(m2 - Mx);
                m = Mx; s = a1 + a2;
            }
        }
        if (lane == 0) {
            float xk = own[row] * K_LOG2;
            pout[row] = NEG_EPS_LN2 * (m + __log2f(s) - xk) + EPS_NEG_LOGMU;
            prevmax[idx] = m;
        }
    }
}

// ---------- sparse Sinkhorn pass v2 (single-pass launch; kept as fallback) ----------
__global__ __launch_bounds__(256) void lse_sparse3_kernel(
    const _Float16* __restrict__ Sxy, const _Float16* __restrict__ STxy,
    const _Float16* __restrict__ Sxx, const _Float16* __restrict__ Syy,
    const float* __restrict__ x2, const float* __restrict__ y2,
    float* __restrict__ Pxy0, float* __restrict__ Pxy1,
    float* __restrict__ Pxx0, float* __restrict__ Pxx1,
    float* __restrict__ Pyy0, float* __restrict__ Pyy1,
    int odd,
    const unsigned int* __restrict__ cand, const int* __restrict__ cnt,
    float* __restrict__ prevmax) {
    int wave = threadIdx.x >> 6, lane = threadIdx.x & 63;
    int gwave = blockIdx.x * 4 + wave;        // 0..3071
    int pair = gwave >> 10;                   // 1024 waves per pair
    int pwave = gwave & 1023;                 // rows pwave*4 .. +3
    const _Float16* M;
    const float *own, *other, *pin;
    float* pout;
    if (pair == 0) {
        if (odd) { M = Sxy;  own = x2; other = y2; pin = Pxy0; pout = Pxy1; }
        else     { M = STxy; own = y2; other = x2; pin = Pxy1; pout = Pxy0; }
    } else if (pair == 1) {
        M = Sxx; own = x2; other = x2;
        if (odd) { pin = Pxx0; pout = Pxx1; } else { pin = Pxx1; pout = Pxx0; }
    } else {
        M = Syy; own = y2; other = y2;
        if (odd) { pin = Pyy0; pout = Pyy1; } else { pin = Pyy1; pout = Pyy0; }
    }
    int set = pair * 2 + (odd ? 0 : 1);
    sparse_rows4(M, own, other, pin, pout, set, pwave, lane, cand, cnt, prevmax);
}

// ---------- per-pair grid barrier (monotonic counter, agent-scope) ----------
// Safe ONLY under cooperative launch (all blocks co-resident). All threads
// execute __threadfence() on both sides so every CU writes back its dirty L2
// lines (cross-XCD release) and invalidates its L1/L2 (acquire) -- per-XCD
// L2s are NOT coherent. Counter is monotonic: no reset race; zeroed by a
// hipMemsetAsync before each cooperative launch.
__device__ __forceinline__ void pair_barrier(unsigned int* ctr, int gen, int nblk) {
    __threadfence();               // release: flush this CU/XCD's dirty lines
    __syncthreads();
    if (threadIdx.x == 0) {
        __hip_atomic_fetch_add(ctr, 1u, __ATOMIC_RELAXED, __HIP_MEMORY_SCOPE_AGENT);
        unsigned int target = (unsigned int)(nblk * gen);
        while (__hip_atomic_load(ctr, __ATOMIC_RELAXED, __HIP_MEMORY_SCOPE_AGENT) < target)
            __builtin_amdgcn_s_sleep(1);
    }
    __syncthreads();
    __threadfence();               // acquire: invalidate stale L1/L2 lines
}

// ---------- persistent sparse phase: passes [p_start, p_end] in ONE launch ----------
// 192 blocks x 1024 threads: pair = blockIdx/64 (64 blocks/pair, 16 waves/block,
// 4 rows/wave -> 4096 rows/pair). The 3 pairs are independent Sinkhorn problems,
// so each pass boundary only needs a barrier among the 64 blocks of ONE pair
// (64 serialized atomic arrivals instead of a 768-block grid sync).
__global__ __launch_bounds__(1024) void sink_sparse_coop(
    const _Float16* __restrict__ Sxy, const _Float16* __restrict__ STxy,
    const _Float16* __restrict__ Sxx, const _Float16* __restrict__ Syy,
    const float* __restrict__ x2, const float* __restrict__ y2,
    float* __restrict__ Pxy0, float* __restrict__ Pxy1,
    float* __restrict__ Pxx0, float* __restrict__ Pxx1,
    float* __restrict__ Pyy0, float* __restrict__ Pyy1,
    const unsigned int* __restrict__ cand, const int* __restrict__ cnt,
    float* __restrict__ prevmax,
    unsigned int* __restrict__ barctr, int p_start, int p_end) {
    int wave = threadIdx.x >> 6, lane = threadIdx.x & 63;   // 16 waves/block
    int pair = blockIdx.x >> 6;                              // 0..2
    int pblk = blockIdx.x & 63;                              // 0..63
    int pwave = pblk * 16 + wave;                            // 0..1023
    unsigned int* ctr = barctr + pair * 32;                  // 128B-separated lines

    for (int p = p_start; p <= p_end; ++p) {
        int odd = p & 1;
        const _Float16* M;
        const float *own, *other, *pin;
        float* pout;
        if (pair == 0) {
            if (odd) { M = Sxy;  own = x2; other = y2; pin = Pxy0; pout = Pxy1; }
            else     { M = STxy; own = y2; other = x2; pin = Pxy1; pout = Pxy0; }
        } else if (pair == 1) {
            M = Sxx; own = x2; other = x2;
            if (odd) { pin = Pxx0; pout = Pxx1; } else { pin = Pxx1; pout = Pxx0; }
        } else {
            M = Syy; own = y2; other = y2;
            if (odd) { pin = Pyy0; pout = Pyy1; } else { pin = Pyy1; pout = Pyy0; }
        }
        int set = pair * 2 + (odd ? 0 : 1);
        sparse_rows4(M, own, other, pin, pout, set, pwave, lane, cand, cnt, prevmax);
        if (p < p_end)
            pair_barrier(ctr, p - p_start + 1, 64);
        // (no barrier after the last pass: end-of-kernel release handles it)
    }
}

// ---------- final: relu( mean(f_xy+g_xy) - 0.5*mean(f_xx+g_xx) - 0.5*mean(f_yy+g_yy) )
__global__ void finalize_kernel(const float* __restrict__ fxy, const float* __restrict__ gxy,
                                const float* __restrict__ fxx, const float* __restrict__ gxx,
                                const float* __restrict__ fyy, const float* __restrict__ gyy,
                                float* __restrict__ out) {
    __shared__ float sb[256];
    float s = 0.f;
    for (int t = threadIdx.x; t < N; t += 256)
        s += (fxy[t] + gxy[t]) - 0.5f * (fxx[t] + gxx[t]) - 0.5f * (fyy[t] + gyy[t]);
    sb[threadIdx.x] = s;
    __syncthreads();
    for (int off = 128; off > 0; off >>= 1) {
        if (threadIdx.x < off) sb[threadIdx.x] += sb[threadIdx.x + off];
        __syncthreads();
    }
    if (threadIdx.x == 0) {
        float v = sb[0] * (1.0f / 4096.0f);
        out[0] = v > 0.f ? v : 0.f;
    }
}

extern "C" void kernel_launch(void* const* d_in, const int* in_sizes, int n_in,
                              void* d_out, int out_size, void* d_ws, size_t ws_size,
                              hipStream_t stream) {
    const float* x = (const float*)d_in[0];
    const float* y = (const float*)d_in[1];

    const size_t SZ_S = (size_t)N * N * sizeof(_Float16);   // 32 MiB
    const size_t SZ_B = (size_t)N * D * sizeof(__bf16);     // 4 MiB
    const size_t SZ_CAND = (size_t)6 * N * CAP * sizeof(unsigned int);  // 48 MiB

    char* w = (char*)d_ws;
    _Float16* Sxy  = (_Float16*)w; w += SZ_S;
    _Float16* STxy = (_Float16*)w; w += SZ_S;
    _Float16* Sxx  = (_Float16*)w; w += SZ_S;
    _Float16* Syy  = (_Float16*)w; w += SZ_S;
    __bf16* xb = (__bf16*)w;       w += SZ_B;
    __bf16* yb = (__bf16*)w;       w += SZ_B;
    unsigned int* cand = (unsigned int*)w; w += SZ_CAND;
    int* cnt = (int*)w;            w += (size_t)6 * N * sizeof(int);
    float* prevmax = (float*)w;    w += (size_t)6 * N * sizeof(float);
    float* x2 = (float*)w;         w += N * sizeof(float);
    float* y2 = (float*)w;         w += N * sizeof(float);
    float* P[6];
    for (int i = 0; i < 6; i++) { P[i] = (float*)w; w += N * sizeof(float); }
    unsigned int* barctr = (unsigned int*)w; w += 3 * 128;   // 3 per-pair barrier lines

    const size_t need = (size_t)(w - (char*)d_ws);
    const bool sparse_ok = (ws_size >= need);

    cvt_bf16_kernel<<<(N * D + 255) / 256, 256, 0, stream>>>(x, xb, N * D);
    cvt_bf16_kernel<<<(N * D + 255) / 256, 256, 0, stream>>>(y, yb, N * D);
    sqnorm_kernel<<<N, 64, 0, stream>>>(x, x2);
    sqnorm_kernel<<<N, 64, 0, stream>>>(y, y2);

    gemm128_kernel<<<dim3(32, 32), 256, 0, stream>>>(xb, yb, Sxy, STxy, 0);
    gemm128_kernel<<<dim3(32, 32), 256, 0, stream>>>(xb, xb, Sxx, Sxx, 1);
    gemm128_kernel<<<dim3(32, 32), 256, 0, stream>>>(yb, yb, Syy, Syy, 1);

    hipMemsetAsync(P[0], 0, N * sizeof(float), stream);  // g0_xy
    hipMemsetAsync(P[2], 0, N * sizeof(float), stream);  // g0_xx
    hipMemsetAsync(P[4], 0, N * sizeof(float), stream);  // g0_yy

    if (!sparse_ok) {
        // workspace too small for candidate machinery: pure dense loop
        for (int p = 1; p <= SINK_PASSES; p++) {
            lse_full3_kernel<0><<<3 * (N / 4), 256, 0, stream>>>(
                Sxy, STxy, Sxx, Syy, x2, y2,
                P[0], P[1], P[2], P[3], P[4], P[5], p & 1, cand, cnt, prevmax);
        }
    } else {
        // dense warmup 1..8, candidate BUILD at 9,10
        for (int p = 1; p <= 10; p++) {
            int odd = p & 1;
            if (p >= 9)
                lse_full3_kernel<1><<<3 * (N / 4), 256, 0, stream>>>(
                    Sxy, STxy, Sxx, Syy, x2, y2,
                    P[0], P[1], P[2], P[3], P[4], P[5], odd, cand, cnt, prevmax);
            else
                lse_full3_kernel<0><<<3 * (N / 4), 256, 0, stream>>>(
                    Sxy, STxy, Sxx, Syy, x2, y2,
                    P[0], P[1], P[2], P[3], P[4], P[5], odd, cand, cnt, prevmax);
        }

        bool coop_ok = true;
        // sparse passes 11..48 in one persistent cooperative launch
        {
            hipMemsetAsync(barctr, 0, 3 * 128, stream);
            int p0 = 11, p1 = 48;
            void* args[] = {&Sxy, &STxy, &Sxx, &Syy, &x2, &y2,
                            &P[0], &P[1], &P[2], &P[3], &P[4], &P[5],
                            &cand, &cnt, &prevmax, &barctr, &p0, &p1};
            if (hipLaunchCooperativeKernel((void*)sink_sparse_coop, dim3(192), dim3(1024),
                                           args, 0, stream) != hipSuccess)
                coop_ok = false;
        }
        if (!coop_ok) {
            for (int p = 11; p <= 48; p++)
                lse_sparse3_kernel<<<768, 256, 0, stream>>>(
                    Sxy, STxy, Sxx, Syy, x2, y2,
                    P[0], P[1], P[2], P[3], P[4], P[5], p & 1, cand, cnt, prevmax);
        }

        // candidate re-BUILD at 49,50 (covers potential drift since build #1)
        for (int p = 49; p <= 50; p++) {
            lse_full3_kernel<1><<<3 * (N / 4), 256, 0, stream>>>(
                Sxy, STxy, Sxx, Syy, x2, y2,
                P[0], P[1], P[2], P[3], P[4], P[5], p & 1, cand, cnt, prevmax);
        }

        // sparse passes 51..100
        if (coop_ok) {
            hipMemsetAsync(barctr, 0, 3 * 128, stream);
            int p0 = 51, p1 = 100;
            void* args[] = {&Sxy, &STxy, &Sxx, &Syy, &x2, &y2,
                            &P[0], &P[1], &P[2], &P[3], &P[4], &P[5],
                            &cand, &cnt, &prevmax, &barctr, &p0, &p1};
            if (hipLaunchCooperativeKernel((void*)sink_sparse_coop, dim3(192), dim3(1024),
                                           args, 0, stream) != hipSuccess)
                coop_ok = false;
        }
        if (!coop_ok) {
            for (int p = 51; p <= 100; p++)
                lse_sparse3_kernel<<<768, 256, 0, stream>>>(
                    Sxy, STxy, Sxx, Syy, x2, y2,
                    P[0], P[1], P[2], P[3], P[4], P[5], p & 1, cand, cnt, prevmax);
        }
    }
    finalize_kernel<<<1, 256, 0, stream>>>(P[1], P[0], P[3], P[2], P[5], P[4],
                                           (float*)d_out);
}